// Round 9
// baseline (50.129 us; speedup 1.0000x reference)
//
#include <hip/hip_runtime.h>
#include <hip/hip_bf16.h>

#define B_TOTAL 65536
#define H 256
#define TS 64
#define NT 2           // tiles per block
#define THREADS 512
#define STRIDE 264   // ushort elems per LDS activation row (528 B = 33*16, b128-aligned)
#define KK 2.8853900817779268f   // 2/ln(2): tanh(x) uses exp2(KK*x)

// workspace layout (ushort offsets)
#define WS_W1   0        // 65536 ushorts : W1 bf16 fragment pack (128 KB)
#define WS_W0B  65536    // 2048 ushorts  : W0 rows bf16 (4 KB)
#define WS_AUX  67584    // 2560 floats   : G4|KB0|KB1|WN|W4 (5 KB, float-addressed)
#define WS_XB   73728    // 524288 ushorts: x bf16 (1 MB)
#define WS_NEED_BYTES (147456 + 1048576)

typedef __attribute__((ext_vector_type(8))) short bf16x8;
typedef __attribute__((ext_vector_type(4))) float f32x4;

// r = 1/(exp2(kz)+1) where kz = KK*x  =>  tanh(x) = 1-2r, 1-tanh^2 = 4r(1-r)
__device__ __forceinline__ float rsig(float kz) {
    float e = __builtin_amdgcn_exp2f(kz);
    return __builtin_amdgcn_rcpf(e + 1.0f);
}
__device__ __forceinline__ void tanh_r(float x, float& t, float& r) {
    r = rsig(KK * x);
    t = fmaf(-2.0f, r, 1.0f);
}
__device__ __forceinline__ float bf2f(ushort b) {
    union { unsigned u; float f; } v; v.u = ((unsigned)b) << 16;
    return v.f;
}
// cold-path scalar conversion (prep kernel W1 pack)
__device__ __forceinline__ ushort f2bf(float f) {
    union { float f; unsigned u; } v; v.f = f;
    unsigned r = v.u + 0x7fffu + ((v.u >> 16) & 1u);
    return (ushort)(r >> 16);
}
__device__ __forceinline__ ushort2 cvt2(float a, float b) {
    union { __hip_bfloat162 h; ushort2 u; } v;
    v.h = __float22bfloat162_rn(make_float2(a, b));
    return v.u;
}
__device__ __forceinline__ bf16x8 pack8(float4 a, float4 b) {
    union { bf16x8 v; ushort2 u[4]; } r;
    r.u[0] = cvt2(a.x, a.y); r.u[1] = cvt2(a.z, a.w);
    r.u[2] = cvt2(b.x, b.y); r.u[3] = cvt2(b.z, b.w);
    return r.v;
}

// PREP: blocks 0-31  -> W1 bf16 fragment pack (R6 lesson: in-loop f32 fragment
//                       builds are uncoalesced -> 2x loss; keep the pack)
//       block 32     -> batch-invariant scalars: G4=4*(W0@W3), KB0=KK*b0,
//                       KB1=KK*b1, WN=-2*W2, W4=4*W2, W0 rows in bf16
//       blocks 33+   -> x packed to bf16 (coalesced 32B->16B per sample)
__global__ void prep(const float* __restrict__ W1, const float* __restrict__ W0,
                     const float* __restrict__ W3, const float* __restrict__ b0,
                     const float* __restrict__ b1, const float* __restrict__ W2,
                     const float* __restrict__ x, ushort* __restrict__ ws) {
    const int blk = blockIdx.x, tid = threadIdx.x;
    if (blk < 32) {
        int g = blk * 256 + tid;   // 0..8191
        int jt = g >> 9;
        int ks = (g >> 6) & 7;
        int l  = g & 63;
        int row = jt * 16 + (l & 15);
        int k0  = ks * 32 + (l >> 4) * 8;
        ushort* dst = ws + WS_W1 + (size_t)g * 8;
        const float* src = W1 + (size_t)row * H + k0;
#pragma unroll
        for (int t = 0; t < 8; ++t) dst[t] = f2bf(src[t]);
    } else if (blk == 32) {
        const int j = tid;
        const float* wr = W0 + (size_t)j * 8;
        float4 wa = *(const float4*)wr, wb = *(const float4*)(wr + 4);
        float4 w3a = *(const float4*)W3, w3b = *(const float4*)(W3 + 4);
        float g0 = wa.x * w3a.x + wa.y * w3a.y + wa.z * w3a.z + wa.w * w3a.w
                 + wb.x * w3b.x + wb.y * w3b.y + wb.z * w3b.z + wb.w * w3b.w;
        float* aux = (float*)(ws + WS_AUX);
        aux[j]        = 4.f * g0;
        aux[256 + j]  = KK * b0[j];
        aux[512 + j]  = KK * b1[j];
        aux[768 + j]  = -2.f * W2[j];
        aux[1024 + j] = 4.f * W2[j];
        *(bf16x8*)(ws + WS_W0B + (size_t)j * 8) = pack8(wa, wb);
    } else {
        const int s = (blk - 33) * 256 + tid;
        const float* xr = x + (size_t)s * 8;
        *(bf16x8*)(ws + WS_XB + (size_t)s * 8) =
            pack8(*(const float4*)xr, *(const float4*)(xr + 4));
    }
}

// fwd:  z1[j][s] = sum_k W1[j][k]*y0[s][k]     (A = W1 rows j)
// bwd:  M[k][s]  = sum_j W1[k][j]*d0g[s][j]    (A = W1 rows k, SAME fragments)
// R8 phase code, but each block runs NT=2 consecutive TS=64 tiles:
// amortizes aux/af loads, final epilogue, and dispatch over 128 samples,
// and prefetches tile-1 x between GEMM(0) and epi2(0) (latency hidden).
// Grid 512 = exactly 2 blocks/CU resident -> single scheduling generation.
template<int XB>
__launch_bounds__(THREADS, 4)
__global__ void fused_mlp(const float* __restrict__ x_batch,
                          const float* __restrict__ scores,
                          const float* __restrict__ b2,
                          const float* __restrict__ W3, const float* __restrict__ b3,
                          const float* __restrict__ cptr,
                          const ushort* __restrict__ ws,
                          float* __restrict__ out) {
    __shared__ ushort Y0[TS][STRIDE];   // y0 bf16   [sample][k] (single buffer)
    __shared__ ushort DG[TS][STRIDE];   // d0g = (1-y0^2)*g0, bf16
    __shared__ float  Z2p[8][NT][TS];   // per-wave, per-tile z2 partials
    __shared__ float  Trp[8][NT][TS];   // per-wave, per-tile trace partials

    const int tid  = threadIdx.x;
    const int lane = tid & 63;
    const int w    = tid >> 6;          // wave 0..7 -> rows [32w, 32w+32)
    const int bs0  = blockIdx.x * (TS * NT);
    const int cl   = lane & 15;
    const int q    = lane >> 4;
    const int rq   = q * 4;
    const int j0   = w * 32;

    const ushort* pW  = ws + WS_W1 + (size_t)(2 * w) * 4096 + (size_t)lane * 8;
    const ushort* w0b = ws + WS_W0B;
    const float*  aux = (const float*)(ws + WS_AUX);
    const float*  G4  = aux;
    const float*  KB0 = aux + 256;
    const float*  KB1 = aux + 512;
    const float*  WN  = aux + 768;
    const float*  W4  = aux + 1024;
    const ushort* xb  = ws + WS_XB;

    // hoisted per-block constants (amortized over NT tiles)
    float4 kb00 = *(const float4*)(KB0 + j0 + rq);
    float4 kb01 = *(const float4*)(KB0 + j0 + 16 + rq);
    float4 g40  = *(const float4*)(G4 + j0 + rq);
    float4 g41  = *(const float4*)(G4 + j0 + 16 + rq);
    float4 kb10 = *(const float4*)(KB1 + j0 + rq);
    float4 kb11 = *(const float4*)(KB1 + j0 + 16 + rq);
    float4 wn0  = *(const float4*)(WN + j0 + rq);
    float4 wn1  = *(const float4*)(WN + j0 + 16 + rq);
    float4 w40  = *(const float4*)(W4 + j0 + rq);
    float4 w41  = *(const float4*)(W4 + j0 + 16 + rq);
    float zp0 = 0.25f * ((w40.x + w40.y) + (w40.z + w40.w)
                       + (w41.x + w41.y) + (w41.z + w41.w));

    // x fragments for the current tile (prefetched one tile ahead)
    bf16x8 bx[4];
#pragma unroll
    for (int st = 0; st < 4; ++st) {
        bf16x8 p = (bf16x8){0, 0, 0, 0, 0, 0, 0, 0};
        if (q == 0) {
            if (XB) {
                p = *(const bf16x8*)(xb + (size_t)(bs0 + st * 16 + cl) * 8);
            } else {
                const float* xr = x_batch + (size_t)(bs0 + st * 16 + cl) * 8;
                p = pack8(*(const float4*)xr, *(const float4*)(xr + 4));
            }
        }
        bx[st] = p;
    }

#pragma unroll
    for (int t = 0; t < NT; ++t) {
        const int bs = bs0 + t * TS;

        // ---- layer 0 via MFMA (K=8 zero-padded to 32) ----
        f32x4 l0[2][4];
        {
            // A-frag: 16B bf16 row load (L1-hot after tile 0)
            bf16x8 af0 = *(const bf16x8*)(w0b + (size_t)(j0 + cl) * 8);
            bf16x8 af1 = *(const bf16x8*)(w0b + (size_t)(j0 + 16 + cl) * 8);
#pragma unroll
            for (int st = 0; st < 4; ++st) {
                f32x4 z = (f32x4){0.f, 0.f, 0.f, 0.f};
                l0[0][st] = __builtin_amdgcn_mfma_f32_16x16x32_bf16(af0, bx[st], z, 0, 0, 0);
                l0[1][st] = __builtin_amdgcn_mfma_f32_16x16x32_bf16(af1, bx[st], z, 0, 0, 0);
            }
        }

        // ---- layer-0 epilogue: Y0 = tanh bf16; DG = 4r(1-r)*g0 bf16 ----
#pragma unroll
        for (int st = 0; st < 4; ++st) {
            const int row = st * 16 + cl;
#pragma unroll
            for (int jt = 0; jt < 2; ++jt) {
                f32x4 z = l0[jt][st];
                float4 kb = jt ? kb01 : kb00;
                float4 g4 = jt ? g41 : g40;
                float r0 = rsig(fmaf(KK, z[0], kb.x));
                float r1 = rsig(fmaf(KK, z[1], kb.y));
                float r2 = rsig(fmaf(KK, z[2], kb.z));
                float r3 = rsig(fmaf(KK, z[3], kb.w));
                float t0 = fmaf(-2.f, r0, 1.f), t1 = fmaf(-2.f, r1, 1.f);
                float t2 = fmaf(-2.f, r2, 1.f), t3 = fmaf(-2.f, r3, 1.f);
                ushort2 lo = cvt2(t0, t1), hi = cvt2(t2, t3);
                ushort4 vv; vv.x = lo.x; vv.y = lo.y; vv.z = hi.x; vv.w = hi.y;
                *(ushort4*)&Y0[row][j0 + jt * 16 + rq] = vv;
                float m0 = r0 * g4.x, m1 = r1 * g4.y, m2 = r2 * g4.z, m3 = r3 * g4.w;
                float d0 = fmaf(-m0, r0, m0), d1 = fmaf(-m1, r1, m1);
                float d2 = fmaf(-m2, r2, m2), d3 = fmaf(-m3, r3, m3);
                lo = cvt2(d0, d1); hi = cvt2(d2, d3);
                vv.x = lo.x; vv.y = lo.y; vv.z = hi.x; vv.w = hi.y;
                *(ushort4*)&DG[row][j0 + jt * 16 + rq] = vv;
            }
        }
        __syncthreads();   // Y0/DG visible

        // ---- merged fwd+bwd GEMM: 16 MFMAs per weight-frag pair ----
        f32x4 facc[2][4], bacc[2][4];
#pragma unroll
        for (int jt = 0; jt < 2; ++jt)
#pragma unroll
            for (int st = 0; st < 4; ++st) {
                facc[jt][st] = (f32x4){0.f, 0.f, 0.f, 0.f};
                bacc[jt][st] = (f32x4){0.f, 0.f, 0.f, 0.f};
            }
#pragma unroll
        for (int ks = 0; ks < 8; ++ks) {
            const int k0 = ks * 32 + q * 8;
            bf16x8 wf0 = *(const bf16x8*)(pW + (size_t)ks * 512);
            bf16x8 wf1 = *(const bf16x8*)(pW + 4096 + (size_t)ks * 512);
#pragma unroll
            for (int st = 0; st < 4; ++st) {
                bf16x8 by = *(const bf16x8*)&Y0[st * 16 + cl][k0];
                bf16x8 bd = *(const bf16x8*)&DG[st * 16 + cl][k0];
                facc[0][st] = __builtin_amdgcn_mfma_f32_16x16x32_bf16(wf0, by, facc[0][st], 0, 0, 0);
                facc[1][st] = __builtin_amdgcn_mfma_f32_16x16x32_bf16(wf1, by, facc[1][st], 0, 0, 0);
                bacc[0][st] = __builtin_amdgcn_mfma_f32_16x16x32_bf16(wf0, bd, bacc[0][st], 0, 0, 0);
                bacc[1][st] = __builtin_amdgcn_mfma_f32_16x16x32_bf16(wf1, bd, bacc[1][st], 0, 0, 0);
            }
        }

        // ---- prefetch next tile's x fragments (VMEM hides under epi2) ----
        if (t + 1 < NT) {
#pragma unroll
            for (int st = 0; st < 4; ++st) {
                bf16x8 p = (bf16x8){0, 0, 0, 0, 0, 0, 0, 0};
                if (q == 0) {
                    if (XB) {
                        p = *(const bf16x8*)(xb + (size_t)(bs0 + TS + st * 16 + cl) * 8);
                    } else {
                        const float* xr = x_batch + (size_t)(bs0 + TS + st * 16 + cl) * 8;
                        p = pack8(*(const float4*)xr, *(const float4*)(xr + 4));
                    }
                }
                bx[st] = p;
            }
        }

        // ---- merged epilogue (VALU diet): z2/trace partials ----
#pragma unroll
        for (int st = 0; st < 4; ++st) {
            float zp = zp0, tp = 0.f;
#pragma unroll
            for (int jt = 0; jt < 2; ++jt) {
                f32x4 z  = facc[jt][st];
                f32x4 mm = bacc[jt][st];
                float4 kb = jt ? kb11 : kb10;
                float4 wn = jt ? wn1 : wn0;
                float4 w4 = jt ? w41 : w40;
                float r0 = rsig(fmaf(KK, z[0], kb.x));
                float r1 = rsig(fmaf(KK, z[1], kb.y));
                float r2 = rsig(fmaf(KK, z[2], kb.z));
                float r3 = rsig(fmaf(KK, z[3], kb.w));
                zp = fmaf(wn.x, r0, zp); zp = fmaf(wn.y, r1, zp);
                zp = fmaf(wn.z, r2, zp); zp = fmaf(wn.w, r3, zp);
                float m0 = r0 * w4.x, m1 = r1 * w4.y, m2 = r2 * w4.z, m3 = r3 * w4.w;
                float a0 = fmaf(-m0, r0, m0), a1 = fmaf(-m1, r1, m1);
                float a2 = fmaf(-m2, r2, m2), a3 = fmaf(-m3, r3, m3);
                tp = fmaf(a0, mm[0], tp); tp = fmaf(a1, mm[1], tp);
                tp = fmaf(a2, mm[2], tp); tp = fmaf(a3, mm[3], tp);
            }
            zp += __shfl_xor(zp, 16);
            zp += __shfl_xor(zp, 32);
            tp += __shfl_xor(tp, 16);
            tp += __shfl_xor(tp, 32);
            if (lane < 16) {
                Z2p[w][t][st * 16 + lane] = zp;
                Trp[w][t][st * 16 + lane] = tp;
            }
        }
        __syncthreads();   // GEMM reads done (tile t) + partials visible
    }

    // ---- final epilogue: 128 samples, threads 0..127 ----
    if (tid < TS * NT) {
        const int tt = tid >> 6, i = tid & 63;
        float z2 = b2[0], tr = 0.f;
#pragma unroll
        for (int k = 0; k < 8; ++k) { z2 += Z2p[k][tt][i]; tr += Trp[k][tt][i]; }
        float y2, r2;
        tanh_r(z2, y2, r2);
        float m2 = 4.0f * r2;
        float dy2 = fmaf(-m2, r2, m2);    // 1 - y2^2
        float4 w3a = *(const float4*)W3;
        float4 w3b = *(const float4*)(W3 + 4);
        float4 b3a = *(const float4*)b3;
        float4 b3b = *(const float4*)(b3 + 4);
        const float* sc = scores + (size_t)(bs0 + tid) * 8;
        float4 s0 = *(const float4*)sc;
        float4 s1 = *(const float4*)(sc + 4);
        float p1 = w3a.x * s0.x + w3a.y * s0.y + w3a.z * s0.z + w3a.w * s0.w
                 + w3b.x * s1.x + w3b.y * s1.y + w3b.z * s1.z + w3b.w * s1.w;
        float p2 = b3a.x * s0.x + b3a.y * s0.y + b3a.z * s0.z + b3a.w * s0.w
                 + b3b.x * s1.x + b3b.y * s1.y + b3b.z * s1.z + b3b.w * s1.w;
        out[bs0 + tid] = cptr[0] + dy2 * tr + fmaf(y2, p1, p2);
    }
}

extern "C" void kernel_launch(void* const* d_in, const int* in_sizes, int n_in,
                              void* d_out, int out_size, void* d_ws, size_t ws_size,
                              hipStream_t stream) {
    const float* x  = (const float*)d_in[0];
    const float* sc = (const float*)d_in[1];
    const float* W0 = (const float*)d_in[2];
    const float* b0 = (const float*)d_in[3];
    const float* W1 = (const float*)d_in[4];
    const float* b1 = (const float*)d_in[5];
    const float* W2 = (const float*)d_in[6];
    const float* b2 = (const float*)d_in[7];
    const float* W3 = (const float*)d_in[8];
    const float* b3 = (const float*)d_in[9];
    const float* c  = (const float*)d_in[10];
    float* out = (float*)d_out;
    ushort* ws = (ushort*)d_ws;

    const bool xb = ws_size >= (size_t)WS_NEED_BYTES;
    hipLaunchKernelGGL(prep, dim3(xb ? 289 : 33), dim3(256), 0, stream,
                       W1, W0, W3, b0, b1, W2, x, ws);
    if (xb) {
        hipLaunchKernelGGL(fused_mlp<1>, dim3(B_TOTAL / (TS * NT)), dim3(THREADS), 0, stream,
                           x, sc, b2, W3, b3, c, ws, out);
    } else {
        hipLaunchKernelGGL(fused_mlp<0>, dim3(B_TOTAL / (TS * NT)), dim3(THREADS), 0, stream,
                           x, sc, b2, W3, b3, c, ws, out);
    }
}

// Round 10
// 34.677 us; speedup vs baseline: 1.4456x; 1.4456x over previous
//
#include <hip/hip_runtime.h>
#include <hip/hip_bf16.h>

#define B_TOTAL 65536
#define H 256
#define TS 64
#define NT 2           // tiles per block
#define THREADS 512
#define STRIDE 264   // ushort elems per LDS activation row (528 B = 33*16, b128-aligned)
#define KK 2.8853900817779268f   // 2/ln(2): tanh(x) uses exp2(KK*x)

// workspace layout (ushort offsets)
#define WS_W1   0        // 65536 ushorts : W1 bf16 fragment pack (128 KB)
#define WS_W0B  65536    // 2048 ushorts  : W0 rows bf16 (4 KB)
#define WS_AUX  67584    // 2560 floats   : G4|KB0|KB1|WN|W4 (5 KB, float-addressed)
#define WS_XB   73728    // 524288 ushorts: x bf16 (1 MB)
#define WS_NEED_BYTES (147456 + 1048576)

typedef __attribute__((ext_vector_type(8))) short bf16x8;
typedef __attribute__((ext_vector_type(4))) float f32x4;

// r = 1/(exp2(kz)+1) where kz = KK*x  =>  tanh(x) = 1-2r, 1-tanh^2 = 4r(1-r)
__device__ __forceinline__ float rsig(float kz) {
    float e = __builtin_amdgcn_exp2f(kz);
    return __builtin_amdgcn_rcpf(e + 1.0f);
}
__device__ __forceinline__ void tanh_r(float x, float& t, float& r) {
    r = rsig(KK * x);
    t = fmaf(-2.0f, r, 1.0f);
}
__device__ __forceinline__ float bf2f(ushort b) {
    union { unsigned u; float f; } v; v.u = ((unsigned)b) << 16;
    return v.f;
}
// cold-path scalar conversion (prep kernel W1 pack)
__device__ __forceinline__ ushort f2bf(float f) {
    union { float f; unsigned u; } v; v.f = f;
    unsigned r = v.u + 0x7fffu + ((v.u >> 16) & 1u);
    return (ushort)(r >> 16);
}
__device__ __forceinline__ ushort2 cvt2(float a, float b) {
    union { __hip_bfloat162 h; ushort2 u; } v;
    v.h = __float22bfloat162_rn(make_float2(a, b));
    return v.u;
}
__device__ __forceinline__ bf16x8 pack8(float4 a, float4 b) {
    union { bf16x8 v; ushort2 u[4]; } r;
    r.u[0] = cvt2(a.x, a.y); r.u[1] = cvt2(a.z, a.w);
    r.u[2] = cvt2(b.x, b.y); r.u[3] = cvt2(b.z, b.w);
    return r.v;
}

// PREP: blocks 0-31  -> W1 bf16 fragment pack (R6 lesson: in-loop f32 fragment
//                       builds are uncoalesced -> 2x loss; keep the pack)
//       block 32     -> batch-invariant scalars: G4=4*(W0@W3), KB0=KK*b0,
//                       KB1=KK*b1, WN=-2*W2, W4=4*W2, W0 rows in bf16
//       blocks 33+   -> x packed to bf16 (coalesced 32B->16B per sample)
__global__ void prep(const float* __restrict__ W1, const float* __restrict__ W0,
                     const float* __restrict__ W3, const float* __restrict__ b0,
                     const float* __restrict__ b1, const float* __restrict__ W2,
                     const float* __restrict__ x, ushort* __restrict__ ws) {
    const int blk = blockIdx.x, tid = threadIdx.x;
    if (blk < 32) {
        int g = blk * 256 + tid;   // 0..8191
        int jt = g >> 9;
        int ks = (g >> 6) & 7;
        int l  = g & 63;
        int row = jt * 16 + (l & 15);
        int k0  = ks * 32 + (l >> 4) * 8;
        ushort* dst = ws + WS_W1 + (size_t)g * 8;
        const float* src = W1 + (size_t)row * H + k0;
#pragma unroll
        for (int t = 0; t < 8; ++t) dst[t] = f2bf(src[t]);
    } else if (blk == 32) {
        const int j = tid;
        const float* wr = W0 + (size_t)j * 8;
        float4 wa = *(const float4*)wr, wb = *(const float4*)(wr + 4);
        float4 w3a = *(const float4*)W3, w3b = *(const float4*)(W3 + 4);
        float g0 = wa.x * w3a.x + wa.y * w3a.y + wa.z * w3a.z + wa.w * w3a.w
                 + wb.x * w3b.x + wb.y * w3b.y + wb.z * w3b.z + wb.w * w3b.w;
        float* aux = (float*)(ws + WS_AUX);
        aux[j]        = 4.f * g0;
        aux[256 + j]  = KK * b0[j];
        aux[512 + j]  = KK * b1[j];
        aux[768 + j]  = -2.f * W2[j];
        aux[1024 + j] = 4.f * W2[j];
        *(bf16x8*)(ws + WS_W0B + (size_t)j * 8) = pack8(wa, wb);
    } else {
        const int s = (blk - 33) * 256 + tid;
        const float* xr = x + (size_t)s * 8;
        *(bf16x8*)(ws + WS_XB + (size_t)s * 8) =
            pack8(*(const float4*)xr, *(const float4*)(xr + 4));
    }
}

// fwd:  z1[j][s] = sum_k W1[j][k]*y0[s][k]     (A = W1 rows j)
// bwd:  M[k][s]  = sum_j W1[k][j]*d0g[s][j]    (A = W1 rows k, SAME fragments)
// NT=2 tiles per block, R8 phase code verbatim inside the tile loop.
// R9 lesson: do NOT hoist aux constants across the GEMM phase -- 41 hoisted
// VGPRs pushed the 64-arch-VGPR budget over -> 40MB scratch spills, 1.6x
// regression. Each phase loads its own constants fresh (L1-hot, no residency).
template<int XB>
__launch_bounds__(THREADS, 4)
__global__ void fused_mlp(const float* __restrict__ x_batch,
                          const float* __restrict__ scores,
                          const float* __restrict__ b2,
                          const float* __restrict__ W3, const float* __restrict__ b3,
                          const float* __restrict__ cptr,
                          const ushort* __restrict__ ws,
                          float* __restrict__ out) {
    __shared__ ushort Y0[TS][STRIDE];   // y0 bf16   [sample][k] (single buffer)
    __shared__ ushort DG[TS][STRIDE];   // d0g = (1-y0^2)*g0, bf16
    __shared__ float  Z2p[8][NT][TS];   // per-wave, per-tile z2 partials
    __shared__ float  Trp[8][NT][TS];   // per-wave, per-tile trace partials

    const int tid  = threadIdx.x;
    const int lane = tid & 63;
    const int w    = tid >> 6;          // wave 0..7 -> rows [32w, 32w+32)
    const int bs0  = blockIdx.x * (TS * NT);
    const int cl   = lane & 15;
    const int q    = lane >> 4;
    const int rq   = q * 4;
    const int j0   = w * 32;

    const ushort* pW  = ws + WS_W1 + (size_t)(2 * w) * 4096 + (size_t)lane * 8;
    const ushort* w0b = ws + WS_W0B;
    const float*  aux = (const float*)(ws + WS_AUX);
    const float*  G4  = aux;
    const float*  KB0 = aux + 256;
    const float*  KB1 = aux + 512;
    const float*  WN  = aux + 768;
    const float*  W4  = aux + 1024;
    const ushort* xb  = ws + WS_XB;

    // x fragments for the current tile (prefetched one tile ahead)
    bf16x8 bx[4];
#pragma unroll
    for (int st = 0; st < 4; ++st) {
        bf16x8 p = (bf16x8){0, 0, 0, 0, 0, 0, 0, 0};
        if (q == 0) {
            if (XB) {
                p = *(const bf16x8*)(xb + (size_t)(bs0 + st * 16 + cl) * 8);
            } else {
                const float* xr = x_batch + (size_t)(bs0 + st * 16 + cl) * 8;
                p = pack8(*(const float4*)xr, *(const float4*)(xr + 4));
            }
        }
        bx[st] = p;
    }

#pragma unroll
    for (int t = 0; t < NT; ++t) {
        // ---- layer 0 via MFMA (K=8 zero-padded to 32) ----
        f32x4 l0[2][4];
        {
            // A-frag: 16B bf16 row load (L1-hot after tile 0)
            bf16x8 af0 = *(const bf16x8*)(w0b + (size_t)(j0 + cl) * 8);
            bf16x8 af1 = *(const bf16x8*)(w0b + (size_t)(j0 + 16 + cl) * 8);
#pragma unroll
            for (int st = 0; st < 4; ++st) {
                f32x4 z = (f32x4){0.f, 0.f, 0.f, 0.f};
                l0[0][st] = __builtin_amdgcn_mfma_f32_16x16x32_bf16(af0, bx[st], z, 0, 0, 0);
                l0[1][st] = __builtin_amdgcn_mfma_f32_16x16x32_bf16(af1, bx[st], z, 0, 0, 0);
            }
        }

        // ---- layer-0 epilogue: Y0 = tanh bf16; DG = 4r(1-r)*g0 bf16 ----
        {
            float4 kb0 = *(const float4*)(KB0 + j0 + rq);
            float4 kb1 = *(const float4*)(KB0 + j0 + 16 + rq);
            float4 g40 = *(const float4*)(G4 + j0 + rq);
            float4 g41 = *(const float4*)(G4 + j0 + 16 + rq);
#pragma unroll
            for (int st = 0; st < 4; ++st) {
                const int row = st * 16 + cl;
#pragma unroll
                for (int jt = 0; jt < 2; ++jt) {
                    f32x4 z = l0[jt][st];
                    float4 kb = jt ? kb1 : kb0;
                    float4 g4 = jt ? g41 : g40;
                    float r0 = rsig(fmaf(KK, z[0], kb.x));
                    float r1 = rsig(fmaf(KK, z[1], kb.y));
                    float r2 = rsig(fmaf(KK, z[2], kb.z));
                    float r3 = rsig(fmaf(KK, z[3], kb.w));
                    float t0 = fmaf(-2.f, r0, 1.f), t1 = fmaf(-2.f, r1, 1.f);
                    float t2 = fmaf(-2.f, r2, 1.f), t3 = fmaf(-2.f, r3, 1.f);
                    ushort2 lo = cvt2(t0, t1), hi = cvt2(t2, t3);
                    ushort4 vv; vv.x = lo.x; vv.y = lo.y; vv.z = hi.x; vv.w = hi.y;
                    *(ushort4*)&Y0[row][j0 + jt * 16 + rq] = vv;
                    float m0 = r0 * g4.x, m1 = r1 * g4.y, m2 = r2 * g4.z, m3 = r3 * g4.w;
                    float d0 = fmaf(-m0, r0, m0), d1 = fmaf(-m1, r1, m1);
                    float d2 = fmaf(-m2, r2, m2), d3 = fmaf(-m3, r3, m3);
                    lo = cvt2(d0, d1); hi = cvt2(d2, d3);
                    vv.x = lo.x; vv.y = lo.y; vv.z = hi.x; vv.w = hi.y;
                    *(ushort4*)&DG[row][j0 + jt * 16 + rq] = vv;
                }
            }
        }
        __syncthreads();   // Y0/DG visible

        // ---- merged fwd+bwd GEMM: 16 MFMAs per weight-frag pair ----
        f32x4 facc[2][4], bacc[2][4];
#pragma unroll
        for (int jt = 0; jt < 2; ++jt)
#pragma unroll
            for (int st = 0; st < 4; ++st) {
                facc[jt][st] = (f32x4){0.f, 0.f, 0.f, 0.f};
                bacc[jt][st] = (f32x4){0.f, 0.f, 0.f, 0.f};
            }
#pragma unroll
        for (int ks = 0; ks < 8; ++ks) {
            const int k0 = ks * 32 + q * 8;
            bf16x8 wf0 = *(const bf16x8*)(pW + (size_t)ks * 512);
            bf16x8 wf1 = *(const bf16x8*)(pW + 4096 + (size_t)ks * 512);
#pragma unroll
            for (int st = 0; st < 4; ++st) {
                bf16x8 by = *(const bf16x8*)&Y0[st * 16 + cl][k0];
                bf16x8 bd = *(const bf16x8*)&DG[st * 16 + cl][k0];
                facc[0][st] = __builtin_amdgcn_mfma_f32_16x16x32_bf16(wf0, by, facc[0][st], 0, 0, 0);
                facc[1][st] = __builtin_amdgcn_mfma_f32_16x16x32_bf16(wf1, by, facc[1][st], 0, 0, 0);
                bacc[0][st] = __builtin_amdgcn_mfma_f32_16x16x32_bf16(wf0, bd, bacc[0][st], 0, 0, 0);
                bacc[1][st] = __builtin_amdgcn_mfma_f32_16x16x32_bf16(wf1, bd, bacc[1][st], 0, 0, 0);
            }
        }

        // ---- prefetch next tile's x fragments (VMEM hides under epi2) ----
        if (t + 1 < NT) {
#pragma unroll
            for (int st = 0; st < 4; ++st) {
                bf16x8 p = (bf16x8){0, 0, 0, 0, 0, 0, 0, 0};
                if (q == 0) {
                    if (XB) {
                        p = *(const bf16x8*)(xb + (size_t)(bs0 + TS + st * 16 + cl) * 8);
                    } else {
                        const float* xr = x_batch + (size_t)(bs0 + TS + st * 16 + cl) * 8;
                        p = pack8(*(const float4*)xr, *(const float4*)(xr + 4));
                    }
                }
                bx[st] = p;
            }
        }

        // ---- merged epilogue (VALU diet): z2/trace partials ----
        {
            float4 kb0 = *(const float4*)(KB1 + j0 + rq);
            float4 kb1 = *(const float4*)(KB1 + j0 + 16 + rq);
            float4 wn0 = *(const float4*)(WN + j0 + rq);
            float4 wn1 = *(const float4*)(WN + j0 + 16 + rq);
            float4 w40 = *(const float4*)(W4 + j0 + rq);
            float4 w41 = *(const float4*)(W4 + j0 + 16 + rq);
            float zp0 = 0.25f * ((w40.x + w40.y) + (w40.z + w40.w)
                               + (w41.x + w41.y) + (w41.z + w41.w));
#pragma unroll
            for (int st = 0; st < 4; ++st) {
                float zp = zp0, tp = 0.f;
#pragma unroll
                for (int jt = 0; jt < 2; ++jt) {
                    f32x4 z  = facc[jt][st];
                    f32x4 mm = bacc[jt][st];
                    float4 kb = jt ? kb1 : kb0;
                    float4 wn = jt ? wn1 : wn0;
                    float4 w4 = jt ? w41 : w40;
                    float r0 = rsig(fmaf(KK, z[0], kb.x));
                    float r1 = rsig(fmaf(KK, z[1], kb.y));
                    float r2 = rsig(fmaf(KK, z[2], kb.z));
                    float r3 = rsig(fmaf(KK, z[3], kb.w));
                    zp = fmaf(wn.x, r0, zp); zp = fmaf(wn.y, r1, zp);
                    zp = fmaf(wn.z, r2, zp); zp = fmaf(wn.w, r3, zp);
                    float m0 = r0 * w4.x, m1 = r1 * w4.y, m2 = r2 * w4.z, m3 = r3 * w4.w;
                    float a0 = fmaf(-m0, r0, m0), a1 = fmaf(-m1, r1, m1);
                    float a2 = fmaf(-m2, r2, m2), a3 = fmaf(-m3, r3, m3);
                    tp = fmaf(a0, mm[0], tp); tp = fmaf(a1, mm[1], tp);
                    tp = fmaf(a2, mm[2], tp); tp = fmaf(a3, mm[3], tp);
                }
                zp += __shfl_xor(zp, 16);
                zp += __shfl_xor(zp, 32);
                tp += __shfl_xor(tp, 16);
                tp += __shfl_xor(tp, 32);
                if (lane < 16) {
                    Z2p[w][t][st * 16 + lane] = zp;
                    Trp[w][t][st * 16 + lane] = tp;
                }
            }
        }
        __syncthreads();   // GEMM reads done (tile t) + partials visible
    }

    // ---- final epilogue: 128 samples, threads 0..127 ----
    if (tid < TS * NT) {
        const int tt = tid >> 6, i = tid & 63;
        float z2 = b2[0], tr = 0.f;
#pragma unroll
        for (int k = 0; k < 8; ++k) { z2 += Z2p[k][tt][i]; tr += Trp[k][tt][i]; }
        float y2, r2;
        tanh_r(z2, y2, r2);
        float m2 = 4.0f * r2;
        float dy2 = fmaf(-m2, r2, m2);    // 1 - y2^2
        float4 w3a = *(const float4*)W3;
        float4 w3b = *(const float4*)(W3 + 4);
        float4 b3a = *(const float4*)b3;
        float4 b3b = *(const float4*)(b3 + 4);
        const float* sc = scores + (size_t)(bs0 + tid) * 8;
        float4 s0 = *(const float4*)sc;
        float4 s1 = *(const float4*)(sc + 4);
        float p1 = w3a.x * s0.x + w3a.y * s0.y + w3a.z * s0.z + w3a.w * s0.w
                 + w3b.x * s1.x + w3b.y * s1.y + w3b.z * s1.z + w3b.w * s1.w;
        float p2 = b3a.x * s0.x + b3a.y * s0.y + b3a.z * s0.z + b3a.w * s0.w
                 + b3b.x * s1.x + b3b.y * s1.y + b3b.z * s1.z + b3b.w * s1.w;
        out[bs0 + tid] = cptr[0] + dy2 * tr + fmaf(y2, p1, p2);
    }
}

extern "C" void kernel_launch(void* const* d_in, const int* in_sizes, int n_in,
                              void* d_out, int out_size, void* d_ws, size_t ws_size,
                              hipStream_t stream) {
    const float* x  = (const float*)d_in[0];
    const float* sc = (const float*)d_in[1];
    const float* W0 = (const float*)d_in[2];
    const float* b0 = (const float*)d_in[3];
    const float* W1 = (const float*)d_in[4];
    const float* b1 = (const float*)d_in[5];
    const float* W2 = (const float*)d_in[6];
    const float* b2 = (const float*)d_in[7];
    const float* W3 = (const float*)d_in[8];
    const float* b3 = (const float*)d_in[9];
    const float* c  = (const float*)d_in[10];
    float* out = (float*)d_out;
    ushort* ws = (ushort*)d_ws;

    const bool xb = ws_size >= (size_t)WS_NEED_BYTES;
    hipLaunchKernelGGL(prep, dim3(xb ? 289 : 33), dim3(256), 0, stream,
                       W1, W0, W3, b0, b1, W2, x, ws);
    if (xb) {
        hipLaunchKernelGGL(fused_mlp<1>, dim3(B_TOTAL / (TS * NT)), dim3(THREADS), 0, stream,
                           x, sc, b2, W3, b3, c, ws, out);
    } else {
        hipLaunchKernelGGL(fused_mlp<0>, dim3(B_TOTAL / (TS * NT)), dim3(THREADS), 0, stream,
                           x, sc, b2, W3, b3, c, ws, out);
    }
}

// Round 11
// 32.301 us; speedup vs baseline: 1.5519x; 1.0736x over previous
//
#include <hip/hip_runtime.h>
#include <hip/hip_bf16.h>

#define B_TOTAL 65536
#define H 256
#define TS 64
#define THREADS 512
#define STRIDE 264   // ushort elems per LDS activation row (528 B = 33*16, b128-aligned)
#define KK 2.8853900817779268f   // 2/ln(2): tanh(x) uses exp2(KK*x)

// workspace layout (ushort offsets)
#define WS_W1   0        // 65536 ushorts : W1 bf16 fragment pack (128 KB)
#define WS_W0B  65536    // 2048 ushorts  : W0 rows bf16 (4 KB)
#define WS_AUX  67584    // 2560 floats   : G4|KB0|KB1|WN|W4 (5 KB, float-addressed)

typedef __attribute__((ext_vector_type(8))) short bf16x8;
typedef __attribute__((ext_vector_type(4))) float f32x4;

// r = 1/(exp2(kz)+1) where kz = KK*x  =>  tanh(x) = 1-2r, 1-tanh^2 = 4r(1-r)
__device__ __forceinline__ float rsig(float kz) {
    float e = __builtin_amdgcn_exp2f(kz);
    return __builtin_amdgcn_rcpf(e + 1.0f);
}
__device__ __forceinline__ void tanh_r(float x, float& t, float& r) {
    r = rsig(KK * x);
    t = fmaf(-2.0f, r, 1.0f);
}
__device__ __forceinline__ float bf2f(ushort b) {
    union { unsigned u; float f; } v; v.u = ((unsigned)b) << 16;
    return v.f;
}
// cold-path scalar conversion (prep kernel W1 pack)
__device__ __forceinline__ ushort f2bf(float f) {
    union { float f; unsigned u; } v; v.f = f;
    unsigned r = v.u + 0x7fffu + ((v.u >> 16) & 1u);
    return (ushort)(r >> 16);
}
__device__ __forceinline__ ushort2 cvt2(float a, float b) {
    union { __hip_bfloat162 h; ushort2 u; } v;
    v.h = __float22bfloat162_rn(make_float2(a, b));
    return v.u;
}
__device__ __forceinline__ bf16x8 pack8(float4 a, float4 b) {
    union { bf16x8 v; ushort2 u[4]; } r;
    r.u[0] = cvt2(a.x, a.y); r.u[1] = cvt2(a.z, a.w);
    r.u[2] = cvt2(b.x, b.y); r.u[3] = cvt2(b.z, b.w);
    return r.v;
}

// PREP (33 blocks only -- R11: x-pack dropped, fused packs x inline; the
// 256-block x-pack cost a full prep->fused dependency drain + 2MB extra HBM):
//   blocks 0-31 -> W1 bf16 fragment pack (R6 lesson: in-loop f32 fragment
//                  builds are uncoalesced -> 2x loss; keep the pack)
//   block 32    -> batch-invariant scalars: G4=4*(W0@W3), KB0=KK*b0,
//                  KB1=KK*b1, WN=-2*W2, W4=4*W2, W0 rows in bf16
__global__ void prep(const float* __restrict__ W1, const float* __restrict__ W0,
                     const float* __restrict__ W3, const float* __restrict__ b0,
                     const float* __restrict__ b1, const float* __restrict__ W2,
                     ushort* __restrict__ ws) {
    const int blk = blockIdx.x, tid = threadIdx.x;
    if (blk < 32) {
        int g = blk * 256 + tid;   // 0..8191
        int jt = g >> 9;
        int ks = (g >> 6) & 7;
        int l  = g & 63;
        int row = jt * 16 + (l & 15);
        int k0  = ks * 32 + (l >> 4) * 8;
        ushort* dst = ws + WS_W1 + (size_t)g * 8;
        const float* src = W1 + (size_t)row * H + k0;
#pragma unroll
        for (int t = 0; t < 8; ++t) dst[t] = f2bf(src[t]);
    } else {
        const int j = tid;
        const float* wr = W0 + (size_t)j * 8;
        float4 wa = *(const float4*)wr, wb = *(const float4*)(wr + 4);
        float4 w3a = *(const float4*)W3, w3b = *(const float4*)(W3 + 4);
        float g0 = wa.x * w3a.x + wa.y * w3a.y + wa.z * w3a.z + wa.w * w3a.w
                 + wb.x * w3b.x + wb.y * w3b.y + wb.z * w3b.z + wb.w * w3b.w;
        float* aux = (float*)(ws + WS_AUX);
        aux[j]        = 4.f * g0;
        aux[256 + j]  = KK * b0[j];
        aux[512 + j]  = KK * b1[j];
        aux[768 + j]  = -2.f * W2[j];
        aux[1024 + j] = 4.f * W2[j];
        *(bf16x8*)(ws + WS_W0B + (size_t)j * 8) = pack8(wa, wb);
    }
}

// fwd:  z1[j][s] = sum_k W1[j][k]*y0[s][k]     (A = W1 rows j)
// bwd:  M[k][s]  = sum_j W1[k][j]*d0g[s][j]    (A = W1 rows k, SAME fragments)
// R8 body verbatim (best measured: 30.9). One tile per block -- R9/R10 lesson:
// anything held across the GEMM phase overruns the 64-arch-VGPR budget
// (64 AGPR acc + launch_bounds(512,4) leaves exactly 64) -> spills/serialization.
// x is loaded f32 and packed inline (q==0 lanes only, ~9 VALU -- headroom per R6).
__launch_bounds__(THREADS, 4)
__global__ void fused_mlp(const float* __restrict__ x_batch,
                          const float* __restrict__ scores,
                          const float* __restrict__ b2,
                          const float* __restrict__ W3, const float* __restrict__ b3,
                          const float* __restrict__ cptr,
                          const ushort* __restrict__ ws,
                          float* __restrict__ out) {
    __shared__ ushort Y0[TS][STRIDE];   // y0 bf16   [sample][k]
    __shared__ ushort DG[TS][STRIDE];   // d0g = (1-y0^2)*g0, bf16
    __shared__ float  Z2p[8][TS];       // per-wave z2 partials
    __shared__ float  Trp[8][TS];       // per-wave trace partials

    const int tid  = threadIdx.x;
    const int lane = tid & 63;
    const int w    = tid >> 6;          // wave 0..7 -> rows [32w, 32w+32)
    const int bs   = blockIdx.x * TS;
    const int cl   = lane & 15;
    const int q    = lane >> 4;
    const int rq   = q * 4;
    const int j0   = w * 32;

    const ushort* pW  = ws + WS_W1 + (size_t)(2 * w) * 4096 + (size_t)lane * 8;
    const ushort* w0b = ws + WS_W0B;
    const float*  aux = (const float*)(ws + WS_AUX);
    const float*  G4  = aux;
    const float*  KB0 = aux + 256;
    const float*  KB1 = aux + 512;
    const float*  WN  = aux + 768;
    const float*  W4  = aux + 1024;

    // ---- layer 0 via MFMA (K=8 zero-padded to 32) ----
    f32x4 l0[2][4];
    {
        bf16x8 bx[4];
#pragma unroll
        for (int st = 0; st < 4; ++st) {
            bf16x8 p = (bf16x8){0, 0, 0, 0, 0, 0, 0, 0};
            if (q == 0) {
                const float* xr = x_batch + (size_t)(bs + st * 16 + cl) * 8;
                p = pack8(*(const float4*)xr, *(const float4*)(xr + 4));
            }
            bx[st] = p;
        }
        // A-frag: 16B bf16 row load (q>0 lanes hold garbage K-slots; B is zero there)
        bf16x8 af0 = *(const bf16x8*)(w0b + (size_t)(j0 + cl) * 8);
        bf16x8 af1 = *(const bf16x8*)(w0b + (size_t)(j0 + 16 + cl) * 8);
#pragma unroll
        for (int st = 0; st < 4; ++st) {
            f32x4 z = (f32x4){0.f, 0.f, 0.f, 0.f};
            l0[0][st] = __builtin_amdgcn_mfma_f32_16x16x32_bf16(af0, bx[st], z, 0, 0, 0);
            l0[1][st] = __builtin_amdgcn_mfma_f32_16x16x32_bf16(af1, bx[st], z, 0, 0, 0);
        }
    }

    // ---- layer-0 epilogue: Y0 = tanh bf16; DG = 4r(1-r)*g0 bf16 ----
    {
        float4 kb0 = *(const float4*)(KB0 + j0 + rq);
        float4 kb1 = *(const float4*)(KB0 + j0 + 16 + rq);
        float4 g40 = *(const float4*)(G4 + j0 + rq);
        float4 g41 = *(const float4*)(G4 + j0 + 16 + rq);
#pragma unroll
        for (int st = 0; st < 4; ++st) {
            const int row = st * 16 + cl;
#pragma unroll
            for (int jt = 0; jt < 2; ++jt) {
                f32x4 z = l0[jt][st];
                float4 kb = jt ? kb1 : kb0;
                float4 g4 = jt ? g41 : g40;
                float r0 = rsig(fmaf(KK, z[0], kb.x));
                float r1 = rsig(fmaf(KK, z[1], kb.y));
                float r2 = rsig(fmaf(KK, z[2], kb.z));
                float r3 = rsig(fmaf(KK, z[3], kb.w));
                float t0 = fmaf(-2.f, r0, 1.f), t1 = fmaf(-2.f, r1, 1.f);
                float t2 = fmaf(-2.f, r2, 1.f), t3 = fmaf(-2.f, r3, 1.f);
                ushort2 lo = cvt2(t0, t1), hi = cvt2(t2, t3);
                ushort4 vv; vv.x = lo.x; vv.y = lo.y; vv.z = hi.x; vv.w = hi.y;
                *(ushort4*)&Y0[row][j0 + jt * 16 + rq] = vv;
                float m0 = r0 * g4.x, m1 = r1 * g4.y, m2 = r2 * g4.z, m3 = r3 * g4.w;
                float d0 = fmaf(-m0, r0, m0), d1 = fmaf(-m1, r1, m1);
                float d2 = fmaf(-m2, r2, m2), d3 = fmaf(-m3, r3, m3);
                lo = cvt2(d0, d1); hi = cvt2(d2, d3);
                vv.x = lo.x; vv.y = lo.y; vv.z = hi.x; vv.w = hi.y;
                *(ushort4*)&DG[row][j0 + jt * 16 + rq] = vv;
            }
        }
    }
    __syncthreads();   // Y0/DG visible (barrier 1 of 2)

    // ---- merged fwd+bwd GEMM: 16 MFMAs per weight-frag pair, JIT B-loads ----
    f32x4 facc[2][4], bacc[2][4];
#pragma unroll
    for (int jt = 0; jt < 2; ++jt)
#pragma unroll
        for (int st = 0; st < 4; ++st) {
            facc[jt][st] = (f32x4){0.f, 0.f, 0.f, 0.f};
            bacc[jt][st] = (f32x4){0.f, 0.f, 0.f, 0.f};
        }
#pragma unroll
    for (int ks = 0; ks < 8; ++ks) {
        const int k0 = ks * 32 + q * 8;
        bf16x8 wf0 = *(const bf16x8*)(pW + (size_t)ks * 512);
        bf16x8 wf1 = *(const bf16x8*)(pW + 4096 + (size_t)ks * 512);
#pragma unroll
        for (int st = 0; st < 4; ++st) {
            bf16x8 by = *(const bf16x8*)&Y0[st * 16 + cl][k0];
            bf16x8 bd = *(const bf16x8*)&DG[st * 16 + cl][k0];
            facc[0][st] = __builtin_amdgcn_mfma_f32_16x16x32_bf16(wf0, by, facc[0][st], 0, 0, 0);
            facc[1][st] = __builtin_amdgcn_mfma_f32_16x16x32_bf16(wf1, by, facc[1][st], 0, 0, 0);
            bacc[0][st] = __builtin_amdgcn_mfma_f32_16x16x32_bf16(wf0, bd, bacc[0][st], 0, 0, 0);
            bacc[1][st] = __builtin_amdgcn_mfma_f32_16x16x32_bf16(wf1, bd, bacc[1][st], 0, 0, 0);
        }
    }

    // ---- merged epilogue (VALU diet): z2/trace partials, no explicit tanh ----
    {
        float4 kb0 = *(const float4*)(KB1 + j0 + rq);
        float4 kb1 = *(const float4*)(KB1 + j0 + 16 + rq);
        float4 wn0 = *(const float4*)(WN + j0 + rq);
        float4 wn1 = *(const float4*)(WN + j0 + 16 + rq);
        float4 w40 = *(const float4*)(W4 + j0 + rq);
        float4 w41 = *(const float4*)(W4 + j0 + 16 + rq);
        float zp0 = 0.25f * ((w40.x + w40.y) + (w40.z + w40.w)
                           + (w41.x + w41.y) + (w41.z + w41.w));
#pragma unroll
        for (int st = 0; st < 4; ++st) {
            float zp = zp0, tp = 0.f;
#pragma unroll
            for (int jt = 0; jt < 2; ++jt) {
                f32x4 z  = facc[jt][st];
                f32x4 mm = bacc[jt][st];
                float4 kb = jt ? kb1 : kb0;
                float4 wn = jt ? wn1 : wn0;
                float4 w4 = jt ? w41 : w40;
                float r0 = rsig(fmaf(KK, z[0], kb.x));
                float r1 = rsig(fmaf(KK, z[1], kb.y));
                float r2 = rsig(fmaf(KK, z[2], kb.z));
                float r3 = rsig(fmaf(KK, z[3], kb.w));
                zp = fmaf(wn.x, r0, zp); zp = fmaf(wn.y, r1, zp);
                zp = fmaf(wn.z, r2, zp); zp = fmaf(wn.w, r3, zp);
                float m0 = r0 * w4.x, m1 = r1 * w4.y, m2 = r2 * w4.z, m3 = r3 * w4.w;
                float a0 = fmaf(-m0, r0, m0), a1 = fmaf(-m1, r1, m1);
                float a2 = fmaf(-m2, r2, m2), a3 = fmaf(-m3, r3, m3);
                tp = fmaf(a0, mm[0], tp); tp = fmaf(a1, mm[1], tp);
                tp = fmaf(a2, mm[2], tp); tp = fmaf(a3, mm[3], tp);
            }
            zp += __shfl_xor(zp, 16);
            zp += __shfl_xor(zp, 32);
            tp += __shfl_xor(tp, 16);
            tp += __shfl_xor(tp, 32);
            if (lane < 16) {
                Z2p[w][st * 16 + lane] = zp;
                Trp[w][st * 16 + lane] = tp;
            }
        }
    }
    __syncthreads();   // barrier 2 of 2

    // ---- final epilogue: out = c + dy2*tr + y2*(w3.sc) + (b3.sc) ----
    if (tid < TS) {
        const int s = tid;
        float z2 = b2[0], tr = 0.f;
#pragma unroll
        for (int k = 0; k < 8; ++k) { z2 += Z2p[k][s]; tr += Trp[k][s]; }
        float y2, r2;
        tanh_r(z2, y2, r2);
        float m2 = 4.0f * r2;
        float dy2 = fmaf(-m2, r2, m2);    // 1 - y2^2
        float4 w3a = *(const float4*)W3;
        float4 w3b = *(const float4*)(W3 + 4);
        float4 b3a = *(const float4*)b3;
        float4 b3b = *(const float4*)(b3 + 4);
        const float* sc = scores + (size_t)(bs + s) * 8;
        float4 s0 = *(const float4*)sc;
        float4 s1 = *(const float4*)(sc + 4);
        float p1 = w3a.x * s0.x + w3a.y * s0.y + w3a.z * s0.z + w3a.w * s0.w
                 + w3b.x * s1.x + w3b.y * s1.y + w3b.z * s1.z + w3b.w * s1.w;
        float p2 = b3a.x * s0.x + b3a.y * s0.y + b3a.z * s0.z + b3a.w * s0.w
                 + b3b.x * s1.x + b3b.y * s1.y + b3b.z * s1.z + b3b.w * s1.w;
        out[bs + s] = cptr[0] + dy2 * tr + fmaf(y2, p1, p2);
    }
}

extern "C" void kernel_launch(void* const* d_in, const int* in_sizes, int n_in,
                              void* d_out, int out_size, void* d_ws, size_t ws_size,
                              hipStream_t stream) {
    const float* x  = (const float*)d_in[0];
    const float* sc = (const float*)d_in[1];
    const float* W0 = (const float*)d_in[2];
    const float* b0 = (const float*)d_in[3];
    const float* W1 = (const float*)d_in[4];
    const float* b1 = (const float*)d_in[5];
    const float* W2 = (const float*)d_in[6];
    const float* b2 = (const float*)d_in[7];
    const float* W3 = (const float*)d_in[8];
    const float* b3 = (const float*)d_in[9];
    const float* c  = (const float*)d_in[10];
    float* out = (float*)d_out;
    ushort* ws = (ushort*)d_ws;

    hipLaunchKernelGGL(prep, dim3(33), dim3(256), 0, stream,
                       W1, W0, W3, b0, b1, W2, ws);
    hipLaunchKernelGGL(fused_mlp, dim3(B_TOTAL / TS), dim3(THREADS), 0, stream,
                       x, sc, b2, W3, b3, c, ws, out);
}

// Round 12
// 30.606 us; speedup vs baseline: 1.6379x; 1.0554x over previous
//
#include <hip/hip_runtime.h>
#include <hip/hip_bf16.h>

#define B_TOTAL 65536
#define H 256
#define TS 64
#define THREADS 512
#define STRIDE 264   // ushort elems per LDS activation row (528 B = 33*16, b128-aligned)
#define KK 2.8853900817779268f   // 2/ln(2): tanh(x) uses exp2(KK*x)

// workspace layout (ushort offsets)
#define WS_W1   0        // 65536 ushorts : W1 bf16 fragment pack (128 KB)
#define WS_W0B  65536    // 2048 ushorts  : W0 rows bf16 (4 KB)
#define WS_AUX  67584    // 2560 floats   : G4|KB0|KB1|WN|W4 (5 KB, float-addressed)
#define WS_XB   73728    // 524288 ushorts: x bf16 (1 MB)
#define WS_SP   598016   // 65536 float2  : (W3.sc, b3.sc) per sample (512 KB)
#define WS_NEED_BYTES ((598016 + 262144) * 2)

typedef __attribute__((ext_vector_type(8))) short bf16x8;
typedef __attribute__((ext_vector_type(4))) float f32x4;

// r = 1/(exp2(kz)+1) where kz = KK*x  =>  tanh(x) = 1-2r, 1-tanh^2 = 4r(1-r)
__device__ __forceinline__ float rsig(float kz) {
    float e = __builtin_amdgcn_exp2f(kz);
    return __builtin_amdgcn_rcpf(e + 1.0f);
}
__device__ __forceinline__ void tanh_r(float x, float& t, float& r) {
    r = rsig(KK * x);
    t = fmaf(-2.0f, r, 1.0f);
}
__device__ __forceinline__ float bf2f(ushort b) {
    union { unsigned u; float f; } v; v.u = ((unsigned)b) << 16;
    return v.f;
}
// cold-path scalar conversion (prep kernel W1 pack)
__device__ __forceinline__ ushort f2bf(float f) {
    union { float f; unsigned u; } v; v.f = f;
    unsigned r = v.u + 0x7fffu + ((v.u >> 16) & 1u);
    return (ushort)(r >> 16);
}
__device__ __forceinline__ ushort2 cvt2(float a, float b) {
    union { __hip_bfloat162 h; ushort2 u; } v;
    v.h = __float22bfloat162_rn(make_float2(a, b));
    return v.u;
}
__device__ __forceinline__ bf16x8 pack8(float4 a, float4 b) {
    union { bf16x8 v; ushort2 u[4]; } r;
    r.u[0] = cvt2(a.x, a.y); r.u[1] = cvt2(a.z, a.w);
    r.u[2] = cvt2(b.x, b.y); r.u[3] = cvt2(b.z, b.w);
    return r.v;
}

// PREP: blocks 0-31   -> W1 bf16 fragment pack (R6 lesson: in-loop f32 builds
//                        are uncoalesced -> 2x loss; keep the pack)
//       block 32      -> batch-invariant scalars: G4=4*(W0@W3), KB0=KK*b0,
//                        KB1=KK*b1, WN=-2*W2, W4=4*W2, W0 rows in bf16
//       blocks 33-288 -> x packed to bf16 (R11 lesson: this moves the cold-HBM
//                        x read off fused's serial block-start critical path)
//       blocks 289+   -> scores dot-products (W3.sc, b3.sc) per sample (same
//                        mechanism applied to fused's block-tail cold load)
__global__ void prep(const float* __restrict__ W1, const float* __restrict__ W0,
                     const float* __restrict__ W3, const float* __restrict__ b0,
                     const float* __restrict__ b1, const float* __restrict__ W2,
                     const float* __restrict__ b3,
                     const float* __restrict__ x, const float* __restrict__ scores,
                     ushort* __restrict__ ws) {
    const int blk = blockIdx.x, tid = threadIdx.x;
    if (blk < 32) {
        int g = blk * 256 + tid;   // 0..8191
        int jt = g >> 9;
        int ks = (g >> 6) & 7;
        int l  = g & 63;
        int row = jt * 16 + (l & 15);
        int k0  = ks * 32 + (l >> 4) * 8;
        ushort* dst = ws + WS_W1 + (size_t)g * 8;
        const float* src = W1 + (size_t)row * H + k0;
#pragma unroll
        for (int t = 0; t < 8; ++t) dst[t] = f2bf(src[t]);
    } else if (blk == 32) {
        const int j = tid;
        const float* wr = W0 + (size_t)j * 8;
        float4 wa = *(const float4*)wr, wb = *(const float4*)(wr + 4);
        float4 w3a = *(const float4*)W3, w3b = *(const float4*)(W3 + 4);
        float g0 = wa.x * w3a.x + wa.y * w3a.y + wa.z * w3a.z + wa.w * w3a.w
                 + wb.x * w3b.x + wb.y * w3b.y + wb.z * w3b.z + wb.w * w3b.w;
        float* aux = (float*)(ws + WS_AUX);
        aux[j]        = 4.f * g0;
        aux[256 + j]  = KK * b0[j];
        aux[512 + j]  = KK * b1[j];
        aux[768 + j]  = -2.f * W2[j];
        aux[1024 + j] = 4.f * W2[j];
        *(bf16x8*)(ws + WS_W0B + (size_t)j * 8) = pack8(wa, wb);
    } else if (blk < 289) {
        const int s = (blk - 33) * 256 + tid;
        const float* xr = x + (size_t)s * 8;
        *(bf16x8*)(ws + WS_XB + (size_t)s * 8) =
            pack8(*(const float4*)xr, *(const float4*)(xr + 4));
    } else {
        const int s = (blk - 289) * 256 + tid;
        const float* sc = scores + (size_t)s * 8;
        float4 s0 = *(const float4*)sc;
        float4 s1 = *(const float4*)(sc + 4);
        float4 w3a = *(const float4*)W3, w3b = *(const float4*)(W3 + 4);
        float4 b3a = *(const float4*)b3, b3b = *(const float4*)(b3 + 4);
        float p1 = w3a.x * s0.x + w3a.y * s0.y + w3a.z * s0.z + w3a.w * s0.w
                 + w3b.x * s1.x + w3b.y * s1.y + w3b.z * s1.z + w3b.w * s1.w;
        float p2 = b3a.x * s0.x + b3a.y * s0.y + b3a.z * s0.z + b3a.w * s0.w
                 + b3b.x * s1.x + b3b.y * s1.y + b3b.z * s1.z + b3b.w * s1.w;
        float2* sp = (float2*)(ws + WS_SP);
        sp[s] = make_float2(p1, p2);
    }
}

// fwd:  z1[j][s] = sum_k W1[j][k]*y0[s][k]     (A = W1 rows j)
// bwd:  M[k][s]  = sum_j W1[k][j]*d0g[s][j]    (A = W1 rows k, SAME fragments)
// R8 body verbatim (best measured: 30.9). One tile per block -- R9/R10 lesson:
// anything held across the GEMM phase overruns the 64-arch-VGPR budget
// (64 AGPR acc + launch_bounds(512,4) leaves exactly 64) -> spills/serialization.
// XB=1: x read pre-packed bf16 (L2-hot); scores read as precomputed float2.
template<int XB>
__launch_bounds__(THREADS, 4)
__global__ void fused_mlp(const float* __restrict__ x_batch,
                          const float* __restrict__ scores,
                          const float* __restrict__ b2,
                          const float* __restrict__ W3, const float* __restrict__ b3,
                          const float* __restrict__ cptr,
                          const ushort* __restrict__ ws,
                          float* __restrict__ out) {
    __shared__ ushort Y0[TS][STRIDE];   // y0 bf16   [sample][k]
    __shared__ ushort DG[TS][STRIDE];   // d0g = (1-y0^2)*g0, bf16
    __shared__ float  Z2p[8][TS];       // per-wave z2 partials
    __shared__ float  Trp[8][TS];       // per-wave trace partials

    const int tid  = threadIdx.x;
    const int lane = tid & 63;
    const int w    = tid >> 6;          // wave 0..7 -> rows [32w, 32w+32)
    const int bs   = blockIdx.x * TS;
    const int cl   = lane & 15;
    const int q    = lane >> 4;
    const int rq   = q * 4;
    const int j0   = w * 32;

    const ushort* pW  = ws + WS_W1 + (size_t)(2 * w) * 4096 + (size_t)lane * 8;
    const ushort* w0b = ws + WS_W0B;
    const float*  aux = (const float*)(ws + WS_AUX);
    const float*  G4  = aux;
    const float*  KB0 = aux + 256;
    const float*  KB1 = aux + 512;
    const float*  WN  = aux + 768;
    const float*  W4  = aux + 1024;
    const ushort* xb  = ws + WS_XB;

    // ---- layer 0 via MFMA (K=8 zero-padded to 32) ----
    f32x4 l0[2][4];
    {
        bf16x8 bx[4];
#pragma unroll
        for (int st = 0; st < 4; ++st) {
            bf16x8 p = (bf16x8){0, 0, 0, 0, 0, 0, 0, 0};
            if (q == 0) {
                if (XB) {
                    p = *(const bf16x8*)(xb + (size_t)(bs + st * 16 + cl) * 8);
                } else {
                    const float* xr = x_batch + (size_t)(bs + st * 16 + cl) * 8;
                    p = pack8(*(const float4*)xr, *(const float4*)(xr + 4));
                }
            }
            bx[st] = p;
        }
        // A-frag: 16B bf16 row load (q>0 lanes hold garbage K-slots; B is zero there)
        bf16x8 af0 = *(const bf16x8*)(w0b + (size_t)(j0 + cl) * 8);
        bf16x8 af1 = *(const bf16x8*)(w0b + (size_t)(j0 + 16 + cl) * 8);
#pragma unroll
        for (int st = 0; st < 4; ++st) {
            f32x4 z = (f32x4){0.f, 0.f, 0.f, 0.f};
            l0[0][st] = __builtin_amdgcn_mfma_f32_16x16x32_bf16(af0, bx[st], z, 0, 0, 0);
            l0[1][st] = __builtin_amdgcn_mfma_f32_16x16x32_bf16(af1, bx[st], z, 0, 0, 0);
        }
    }

    // ---- layer-0 epilogue: Y0 = tanh bf16; DG = 4r(1-r)*g0 bf16 ----
    {
        float4 kb0 = *(const float4*)(KB0 + j0 + rq);
        float4 kb1 = *(const float4*)(KB0 + j0 + 16 + rq);
        float4 g40 = *(const float4*)(G4 + j0 + rq);
        float4 g41 = *(const float4*)(G4 + j0 + 16 + rq);
#pragma unroll
        for (int st = 0; st < 4; ++st) {
            const int row = st * 16 + cl;
#pragma unroll
            for (int jt = 0; jt < 2; ++jt) {
                f32x4 z = l0[jt][st];
                float4 kb = jt ? kb1 : kb0;
                float4 g4 = jt ? g41 : g40;
                float r0 = rsig(fmaf(KK, z[0], kb.x));
                float r1 = rsig(fmaf(KK, z[1], kb.y));
                float r2 = rsig(fmaf(KK, z[2], kb.z));
                float r3 = rsig(fmaf(KK, z[3], kb.w));
                float t0 = fmaf(-2.f, r0, 1.f), t1 = fmaf(-2.f, r1, 1.f);
                float t2 = fmaf(-2.f, r2, 1.f), t3 = fmaf(-2.f, r3, 1.f);
                ushort2 lo = cvt2(t0, t1), hi = cvt2(t2, t3);
                ushort4 vv; vv.x = lo.x; vv.y = lo.y; vv.z = hi.x; vv.w = hi.y;
                *(ushort4*)&Y0[row][j0 + jt * 16 + rq] = vv;
                float m0 = r0 * g4.x, m1 = r1 * g4.y, m2 = r2 * g4.z, m3 = r3 * g4.w;
                float d0 = fmaf(-m0, r0, m0), d1 = fmaf(-m1, r1, m1);
                float d2 = fmaf(-m2, r2, m2), d3 = fmaf(-m3, r3, m3);
                lo = cvt2(d0, d1); hi = cvt2(d2, d3);
                vv.x = lo.x; vv.y = lo.y; vv.z = hi.x; vv.w = hi.y;
                *(ushort4*)&DG[row][j0 + jt * 16 + rq] = vv;
            }
        }
    }
    __syncthreads();   // Y0/DG visible (barrier 1 of 2)

    // ---- merged fwd+bwd GEMM: 16 MFMAs per weight-frag pair, JIT B-loads ----
    f32x4 facc[2][4], bacc[2][4];
#pragma unroll
    for (int jt = 0; jt < 2; ++jt)
#pragma unroll
        for (int st = 0; st < 4; ++st) {
            facc[jt][st] = (f32x4){0.f, 0.f, 0.f, 0.f};
            bacc[jt][st] = (f32x4){0.f, 0.f, 0.f, 0.f};
        }
#pragma unroll
    for (int ks = 0; ks < 8; ++ks) {
        const int k0 = ks * 32 + q * 8;
        bf16x8 wf0 = *(const bf16x8*)(pW + (size_t)ks * 512);
        bf16x8 wf1 = *(const bf16x8*)(pW + 4096 + (size_t)ks * 512);
#pragma unroll
        for (int st = 0; st < 4; ++st) {
            bf16x8 by = *(const bf16x8*)&Y0[st * 16 + cl][k0];
            bf16x8 bd = *(const bf16x8*)&DG[st * 16 + cl][k0];
            facc[0][st] = __builtin_amdgcn_mfma_f32_16x16x32_bf16(wf0, by, facc[0][st], 0, 0, 0);
            facc[1][st] = __builtin_amdgcn_mfma_f32_16x16x32_bf16(wf1, by, facc[1][st], 0, 0, 0);
            bacc[0][st] = __builtin_amdgcn_mfma_f32_16x16x32_bf16(wf0, bd, bacc[0][st], 0, 0, 0);
            bacc[1][st] = __builtin_amdgcn_mfma_f32_16x16x32_bf16(wf1, bd, bacc[1][st], 0, 0, 0);
        }
    }

    // ---- merged epilogue (VALU diet): z2/trace partials, no explicit tanh ----
    {
        float4 kb0 = *(const float4*)(KB1 + j0 + rq);
        float4 kb1 = *(const float4*)(KB1 + j0 + 16 + rq);
        float4 wn0 = *(const float4*)(WN + j0 + rq);
        float4 wn1 = *(const float4*)(WN + j0 + 16 + rq);
        float4 w40 = *(const float4*)(W4 + j0 + rq);
        float4 w41 = *(const float4*)(W4 + j0 + 16 + rq);
        float zp0 = 0.25f * ((w40.x + w40.y) + (w40.z + w40.w)
                           + (w41.x + w41.y) + (w41.z + w41.w));
#pragma unroll
        for (int st = 0; st < 4; ++st) {
            float zp = zp0, tp = 0.f;
#pragma unroll
            for (int jt = 0; jt < 2; ++jt) {
                f32x4 z  = facc[jt][st];
                f32x4 mm = bacc[jt][st];
                float4 kb = jt ? kb1 : kb0;
                float4 wn = jt ? wn1 : wn0;
                float4 w4 = jt ? w41 : w40;
                float r0 = rsig(fmaf(KK, z[0], kb.x));
                float r1 = rsig(fmaf(KK, z[1], kb.y));
                float r2 = rsig(fmaf(KK, z[2], kb.z));
                float r3 = rsig(fmaf(KK, z[3], kb.w));
                zp = fmaf(wn.x, r0, zp); zp = fmaf(wn.y, r1, zp);
                zp = fmaf(wn.z, r2, zp); zp = fmaf(wn.w, r3, zp);
                float m0 = r0 * w4.x, m1 = r1 * w4.y, m2 = r2 * w4.z, m3 = r3 * w4.w;
                float a0 = fmaf(-m0, r0, m0), a1 = fmaf(-m1, r1, m1);
                float a2 = fmaf(-m2, r2, m2), a3 = fmaf(-m3, r3, m3);
                tp = fmaf(a0, mm[0], tp); tp = fmaf(a1, mm[1], tp);
                tp = fmaf(a2, mm[2], tp); tp = fmaf(a3, mm[3], tp);
            }
            zp += __shfl_xor(zp, 16);
            zp += __shfl_xor(zp, 32);
            tp += __shfl_xor(tp, 16);
            tp += __shfl_xor(tp, 32);
            if (lane < 16) {
                Z2p[w][st * 16 + lane] = zp;
                Trp[w][st * 16 + lane] = tp;
            }
        }
    }
    __syncthreads();   // barrier 2 of 2

    // ---- final epilogue: out = c + dy2*tr + y2*p1 + p2 ----
    if (tid < TS) {
        const int s = tid;
        float z2 = b2[0], tr = 0.f;
#pragma unroll
        for (int k = 0; k < 8; ++k) { z2 += Z2p[k][s]; tr += Trp[k][s]; }
        float y2, r2;
        tanh_r(z2, y2, r2);
        float m2 = 4.0f * r2;
        float dy2 = fmaf(-m2, r2, m2);    // 1 - y2^2
        float p1, p2;
        if (XB) {
            const float2* sp = (const float2*)(ws + WS_SP);
            float2 pv = sp[bs + s];
            p1 = pv.x; p2 = pv.y;
        } else {
            float4 w3a = *(const float4*)W3;
            float4 w3b = *(const float4*)(W3 + 4);
            float4 b3a = *(const float4*)b3;
            float4 b3b = *(const float4*)(b3 + 4);
            const float* sc = scores + (size_t)(bs + s) * 8;
            float4 s0 = *(const float4*)sc;
            float4 s1 = *(const float4*)(sc + 4);
            p1 = w3a.x * s0.x + w3a.y * s0.y + w3a.z * s0.z + w3a.w * s0.w
               + w3b.x * s1.x + w3b.y * s1.y + w3b.z * s1.z + w3b.w * s1.w;
            p2 = b3a.x * s0.x + b3a.y * s0.y + b3a.z * s0.z + b3a.w * s0.w
               + b3b.x * s1.x + b3b.y * s1.y + b3b.z * s1.z + b3b.w * s1.w;
        }
        out[bs + s] = cptr[0] + dy2 * tr + fmaf(y2, p1, p2);
    }
}

extern "C" void kernel_launch(void* const* d_in, const int* in_sizes, int n_in,
                              void* d_out, int out_size, void* d_ws, size_t ws_size,
                              hipStream_t stream) {
    const float* x  = (const float*)d_in[0];
    const float* sc = (const float*)d_in[1];
    const float* W0 = (const float*)d_in[2];
    const float* b0 = (const float*)d_in[3];
    const float* W1 = (const float*)d_in[4];
    const float* b1 = (const float*)d_in[5];
    const float* W2 = (const float*)d_in[6];
    const float* b2 = (const float*)d_in[7];
    const float* W3 = (const float*)d_in[8];
    const float* b3 = (const float*)d_in[9];
    const float* c  = (const float*)d_in[10];
    float* out = (float*)d_out;
    ushort* ws = (ushort*)d_ws;

    const bool xb = ws_size >= (size_t)WS_NEED_BYTES;
    hipLaunchKernelGGL(prep, dim3(xb ? 545 : 33), dim3(256), 0, stream,
                       W1, W0, W3, b0, b1, W2, b3, x, sc, ws);
    if (xb) {
        hipLaunchKernelGGL(fused_mlp<1>, dim3(B_TOTAL / TS), dim3(THREADS), 0, stream,
                           x, sc, b2, W3, b3, c, ws, out);
    } else {
        hipLaunchKernelGGL(fused_mlp<0>, dim3(B_TOTAL / TS), dim3(THREADS), 0, stream,
                           x, sc, b2, W3, b3, c, ws, out);
    }
}